// Round 14
// baseline (1954.688 us; speedup 1.0000x reference)
//
#include <hip/hip_runtime.h>
#include <stdint.h>

typedef unsigned short ushort_t;
typedef __attribute__((ext_vector_type(8))) short short8;
typedef __attribute__((ext_vector_type(4))) float f32x4;

#define N_NODES 10000
#define MP      10240      // 80 * 128
#define E_EDGES 320000
#define D_IN    3000
#define K1P     3008       // 94 * 32
#define H1      1024
#define H2      128

// ---------- bf16 helpers ----------
static __device__ __forceinline__ float b2f(ushort_t u) {
  union { uint32_t u; float f; } x; x.u = ((uint32_t)u) << 16; return x.f;
}
static __device__ __forceinline__ ushort_t f2b(float f) {
  union { float f; uint32_t u; } x; x.f = f;
  uint32_t r = x.u + 0x7FFF + ((x.u >> 16) & 1);
  return (ushort_t)(r >> 16);
}

// ---------- async global->LDS (16B per lane) ----------
static __device__ __forceinline__ void gload16(const void* g, void* l) {
  __builtin_amdgcn_global_load_lds(
      (const __attribute__((address_space(1))) uint32_t*)g,
      (__attribute__((address_space(3))) uint32_t*)l, 16, 0, 0);
}

// ---------- CSR build ----------
__global__ void zero_k(int* p, int n) {
  int i = blockIdx.x * 256 + threadIdx.x;
  if (i < n) p[i] = 0;
}
__global__ void count_k(const int* __restrict__ ed, int* __restrict__ cnt) {
  int e = blockIdx.x * 256 + threadIdx.x;
  if (e < E_EDGES) atomicAdd(&cnt[ed[e]], 1);
}
__global__ void scan_k(const int* __restrict__ cnt, int* __restrict__ rs, int* __restrict__ cur) {
  __shared__ int sums[256];
  int t = threadIdx.x;
  const int per = 40;
  int base = t * per;
  int s = 0;
  for (int i = 0; i < per; i++) { int idx = base + i; if (idx < N_NODES) s += cnt[idx]; }
  sums[t] = s;
  __syncthreads();
  if (t == 0) { int run = 0; for (int i = 0; i < 256; i++) { int v = sums[i]; sums[i] = run; run += v; } }
  __syncthreads();
  int run = sums[t];
  for (int i = 0; i < per; i++) {
    int idx = base + i;
    if (idx < N_NODES) { rs[idx] = run; cur[idx] = run; run += cnt[idx]; }
  }
  if (t == 255) rs[N_NODES] = run;
}
__global__ void fill_k(const int* __restrict__ es, const int* __restrict__ ed,
                       const float* __restrict__ ew,
                       int* __restrict__ cur, int* __restrict__ psrc, float* __restrict__ pw) {
  int e = blockIdx.x * 256 + threadIdx.x;
  if (e >= E_EDGES) return;
  int d = ed[e];
  int pos = atomicAdd(&cur[d], 1);
  psrc[pos] = es[e];
  pw[pos] = ew[e];
}

// ---------- x conversion ----------
__global__ void conv_x_k(const float* __restrict__ x, ushort_t* __restrict__ xb) {
  int g = blockIdx.x * 256 + threadIdx.x;
  int row = g / 376;
  int c8 = (g % 376) * 8;
  float v[8];
  if (row < N_NODES && c8 < 3000) {
    const float4 f0 = *(const float4*)(x + (size_t)row * 3000 + c8);
    const float4 f1 = *(const float4*)(x + (size_t)row * 3000 + c8 + 4);
    v[0]=f0.x; v[1]=f0.y; v[2]=f0.z; v[3]=f0.w;
    v[4]=f1.x; v[5]=f1.y; v[6]=f1.z; v[7]=f1.w;
  } else {
#pragma unroll
    for (int i = 0; i < 8; i++) v[i] = 0.f;
  }
  uint32_t o0 = (uint32_t)f2b(v[0]) | ((uint32_t)f2b(v[1]) << 16);
  uint32_t o1 = (uint32_t)f2b(v[2]) | ((uint32_t)f2b(v[3]) << 16);
  uint32_t o2 = (uint32_t)f2b(v[4]) | ((uint32_t)f2b(v[5]) << 16);
  uint32_t o3 = (uint32_t)f2b(v[6]) | ((uint32_t)f2b(v[7]) << 16);
  uint4 ov; ov.x=o0; ov.y=o1; ov.z=o2; ov.w=o3;
  *(uint4*)&xb[(size_t)row * K1P + c8] = ov;
}

// ---------- fused weight transpose+convert ----------
struct Seg { const float* src; ushort_t* dst; int K, Nn, Kp, Np, tilesN, blk0; };
struct SegPack { Seg s[8]; };
__global__ void conv_w_all_k(SegPack P) {
  __shared__ float tile[32][33];
  int b = blockIdx.x;
  int si = 0;
#pragma unroll
  for (int i = 1; i < 8; ++i) if (b >= P.s[i].blk0) si = i;
  Seg sg = P.s[si];
  int rel = b - sg.blk0;
  int tk = rel / sg.tilesN, tn = rel % sg.tilesN;
  int tx = threadIdx.x & 31, ty0 = threadIdx.x >> 5;
#pragma unroll
  for (int i = 0; i < 4; ++i) {
    int ty = ty0 + i * 8;
    int k = tk * 32 + ty, n = tn * 32 + tx;
    tile[ty][tx] = (k < sg.K && n < sg.Nn) ? sg.src[(size_t)k * sg.Nn + n] : 0.f;
  }
  __syncthreads();
#pragma unroll
  for (int i = 0; i < 4; ++i) {
    int ty = ty0 + i * 8;
    int n = tn * 32 + ty, k = tk * 32 + tx;
    sg.dst[(size_t)n * sg.Kp + k] = f2b(tile[tx][ty]);
  }
}

// ---------- small 128x128 GEMM (tiny GEMMs only) ----------
template<int EPI>
__global__ __launch_bounds__(256)
void gemm_bt(const ushort_t* __restrict__ A, const ushort_t* __restrict__ BT, int K,
             void* __restrict__ outp, int ldOut, int realM, int realN,
             const float* __restrict__ bias, const float* __restrict__ bng,
             const float* __restrict__ bnb)
{
  __shared__ ushort_t lA[128 * 32];
  __shared__ ushort_t lB[128 * 32];
  const int tid  = threadIdx.x;
  const int row0 = blockIdx.x * 128;
  const int col0 = blockIdx.y * 128;
  const int lane = tid & 63;
  const int wave = tid >> 6;
  const int wr = (wave >> 1) * 64, wc = (wave & 1) * 64;
  const int fr = lane & 15, fq = lane >> 4;

  f32x4 acc[4][4] = {};

  const int rA = tid >> 2;
  const int cA = (tid & 3) * 8;
  const ushort_t* Ab = A  + (size_t)(row0 + rA) * K + cA;
  const ushort_t* Bb = BT + (size_t)(col0 + rA) * K + cA;
  ushort_t* lA0 = &lA[tid * 8];
  ushort_t* lA1 = &lA[2048 + tid * 8];
  ushort_t* lB0 = &lB[tid * 8];
  ushort_t* lB1 = &lB[2048 + tid * 8];
  const size_t rstep = (size_t)64 * K;

  for (int k0 = 0; k0 < K; k0 += 32) {
    gload16(Ab + k0,         lA0);
    gload16(Ab + rstep + k0, lA1);
    gload16(Bb + k0,         lB0);
    gload16(Bb + rstep + k0, lB1);
    __syncthreads();
    short8 af[4], bv[4];
#pragma unroll
    for (int m = 0; m < 4; m++) af[m] = *(const short8*)&lA[(wr + m * 16 + fr) * 32 + fq * 8];
#pragma unroll
    for (int n = 0; n < 4; n++) bv[n] = *(const short8*)&lB[(wc + n * 16 + fr) * 32 + fq * 8];
#pragma unroll
    for (int m = 0; m < 4; m++)
#pragma unroll
      for (int n = 0; n < 4; n++)
        acc[m][n] = __builtin_amdgcn_mfma_f32_16x16x32_bf16(af[m], bv[n], acc[m][n], 0, 0, 0);
    __syncthreads();
  }

  const float inv = 0.9999950000374997f;
#pragma unroll
  for (int n = 0; n < 4; n++) {
    int col = col0 + wc + n * 16 + fr;
    float s = 0.f, t = 0.f, bb = 0.f;
    if (EPI == 1) { s = inv * bng[col]; t = bias[col] * s + bnb[col]; }
    if (EPI == 2) { bb = (col < realN) ? bias[col] : 0.f; }
#pragma unroll
    for (int m = 0; m < 4; m++) {
      int rowb = row0 + wr + m * 16 + fq * 4;
#pragma unroll
      for (int r = 0; r < 4; r++) {
        int row = rowb + r;
        float v = acc[m][n][r];
        if (EPI == 0) {
          ((ushort_t*)outp)[(size_t)row * ldOut + col] = f2b(v);
        } else if (EPI == 1) {
          v = fmaxf(v * s + t, 0.f);
          ((ushort_t*)outp)[(size_t)row * ldOut + col] = f2b(v);
        } else if (EPI == 2) {
          if (row < realM && col < realN)
            ((float*)outp)[(size_t)row * ldOut + col] = v + bb;
        } else {
          if (row < realM && col < realN)
            ((float*)outp)[(size_t)row * ldOut + col] = v;
        }
      }
    }
  }
}

// ---------- gemm3: 128x256 tile, 4 waves, per-wave 128x64 (MR=8,NR=4), BK=32.
// OCCUPANCY BUILD: 2 LDS buffers (48KB), depth-1 prefetch, vmcnt(0) drain,
// launch_bounds(256,3) -> 3 blocks/CU (12 waves/CU) so sibling blocks cover
// load latency (m97/m114 regime). Row-major XCD-chunk traversal for A-panel reuse.
template<int EPI>
__global__ __launch_bounds__(256, 3)
void gemm3(const ushort_t* __restrict__ A, const ushort_t* __restrict__ BT, int K,
           void* __restrict__ outp, int ldOut, int realM, int realN,
           const float* __restrict__ bias, const float* __restrict__ bng,
           const float* __restrict__ bnb)
{
  __shared__ ushort_t lA[2 * 128 * 32];
  __shared__ ushort_t lB[2 * 256 * 32];
  const int tid = threadIdx.x;
  const int wn  = tid >> 6;                 // 4 waves split N
  const int fr  = tid & 15, fq = (tid >> 4) & 3;

  int gy = gridDim.y;                        // # of 256-col tiles
  int nwg = gridDim.x * gy;
  int bid = blockIdx.y * gridDim.x + blockIdx.x;
  int q8 = nwg >> 3, r8 = nwg & 7;
  int xcd = bid & 7, j = bid >> 3;
  int swz = (xcd < r8 ? xcd * (q8 + 1) : r8 * (q8 + 1) + (xcd - r8) * q8) + j;
  const int row0 = (swz / gy) * 128;         // row-major: col fastest
  const int col0 = (swz % gy) * 256;

  f32x4 acc[8][4] = {};

  auto stA = [&](int p, int kt, int r) {
    int c = r * 256 + tid;
    int row = c >> 2, slot = c & 3;
    int ss = slot ^ ((row >> 1) & 3);              // pre-swizzled SOURCE
    gload16(A + (size_t)(row0 + row) * K + kt * 32 + ss * 8,
            &lA[p * (128 * 32) + c * 8]);          // linear LDS dest
  };
  auto stB = [&](int p, int kt, int r) {
    int c = r * 256 + tid;
    int row = c >> 2, slot = c & 3;
    int ss = slot ^ ((row >> 1) & 3);
    gload16(BT + (size_t)(col0 + row) * K + kt * 32 + ss * 8,
            &lB[p * (256 * 32) + c * 8]);
  };
  auto stage = [&](int p, int kt) {
    stA(p, kt, 0); stA(p, kt, 1);
    stB(p, kt, 0); stB(p, kt, 1); stB(p, kt, 2); stB(p, kt, 3);
  };

  const int NT = K >> 5;                    // all uses: >= 4
  stage(0, 0);

  for (int t = 0; t < NT; ++t) {
    const int p = t & 1;
    const int q = p ^ 1;                    // holds tile t-1; reads done pre-barrier
    const int ts = (t + 1 < NT) ? t + 1 : NT - 1;  // clamped dummy restage on tail
    // drain tile t's 6 loads (issued last iter / prologue)
    asm volatile("s_waitcnt vmcnt(0)" ::: "memory");
    __builtin_amdgcn_s_barrier();
    asm volatile("" ::: "memory");
    stage(q, ts);

    short8 bf[4], af[8];
#pragma unroll
    for (int n = 0; n < 4; ++n) {
      int rb = wn * 64 + n * 16 + fr;
      bf[n] = *(const short8*)&lB[p * (256 * 32) + rb * 32 + ((fq ^ ((rb >> 1) & 3)) * 8)];
    }
#pragma unroll
    for (int m = 0; m < 8; ++m) {
      int ra = m * 16 + fr;
      af[m] = *(const short8*)&lA[p * (128 * 32) + ra * 32 + ((fq ^ ((ra >> 1) & 3)) * 8)];
    }
    __builtin_amdgcn_s_setprio(1);
#pragma unroll
    for (int m = 0; m < 8; ++m)
#pragma unroll
      for (int n = 0; n < 4; ++n)
        acc[m][n] = __builtin_amdgcn_mfma_f32_16x16x32_bf16(af[m], bf[n], acc[m][n], 0, 0, 0);
    __builtin_amdgcn_s_setprio(0);
    asm volatile("" ::: "memory");
  }

  const float inv = 0.9999950000374997f;
#pragma unroll
  for (int n = 0; n < 4; ++n) {
    int col = col0 + wn * 64 + n * 16 + fr;
    float sc = 0.f, tc = 0.f, bb = 0.f;
    if (EPI == 1) { sc = inv * bng[col]; tc = bias[col] * sc + bnb[col]; }
    if (EPI == 2) { bb = (col < realN) ? bias[col] : 0.f; }
#pragma unroll
    for (int m = 0; m < 8; ++m) {
      int rowb = row0 + m * 16 + fq * 4;
      if (EPI == 4) {
        // C symmetric: store lane's 4 consecutive rows as 4 consecutive cols of row `col`
        if (col < realN && rowb < realM) {
          if (rowb + 4 <= realM) {
            float4 v4; v4.x = acc[m][n][0]; v4.y = acc[m][n][1];
            v4.z = acc[m][n][2]; v4.w = acc[m][n][3];
            *(float4*)((float*)outp + (size_t)col * ldOut + rowb) = v4;
          } else {
            for (int r = 0; r < realM - rowb; ++r)
              ((float*)outp)[(size_t)col * ldOut + rowb + r] = acc[m][n][r];
          }
        }
      } else {
#pragma unroll
        for (int r = 0; r < 4; ++r) {
          int row = rowb + r;
          float v = acc[m][n][r];
          if (EPI == 0) {
            ((ushort_t*)outp)[(size_t)row * ldOut + col] = f2b(v);
          } else if (EPI == 1) {
            v = fmaxf(v * sc + tc, 0.f);
            ((ushort_t*)outp)[(size_t)row * ldOut + col] = f2b(v);
          } else if (EPI == 2) {
            if (row < realM && col < realN)
              ((float*)outp)[(size_t)row * ldOut + col] = v + bb;
          }
        }
      }
    }
  }
}

// ---------- spmm1 L2-chunked + unroll-8 gather ----------
__global__ void spmm1c_k(const ushort_t* __restrict__ h, ushort_t* __restrict__ o,
                         const int* __restrict__ rs, const int* __restrict__ psrc,
                         const float* __restrict__ pw) {
  const int chunk = blockIdx.y;
  const int dst = blockIdx.x * 4 + (threadIdx.x >> 6);
  const int lane = threadIdx.x & 63;
  const int c0 = chunk * 128 + lane * 2;
  float a0 = 0.f, a1 = 0.f;
  if (dst < N_NODES) {
    const int s0 = rs[dst], e0 = rs[dst + 1];
    int i = s0;
    for (; i + 8 <= e0; i += 8) {
      int   sr[8]; float wv[8]; uint32_t v[8];
#pragma unroll
      for (int u = 0; u < 8; ++u) { sr[u] = psrc[i + u]; wv[u] = pw[i + u]; }
#pragma unroll
      for (int u = 0; u < 8; ++u) v[u] = *(const uint32_t*)&h[(size_t)sr[u] * H1 + c0];
#pragma unroll
      for (int u = 0; u < 8; ++u) {
        a0 += wv[u] * b2f((ushort_t)(v[u] & 0xffff));
        a1 += wv[u] * b2f((ushort_t)(v[u] >> 16));
      }
    }
    for (; i < e0; ++i) {
      float wv = pw[i];
      uint32_t v = *(const uint32_t*)&h[(size_t)psrc[i] * H1 + c0];
      a0 += wv * b2f((ushort_t)(v & 0xffff));
      a1 += wv * b2f((ushort_t)(v >> 16));
    }
  }
  uint32_t ov = (uint32_t)f2b(fmaxf(a0, 0.f)) | ((uint32_t)f2b(fmaxf(a1, 0.f)) << 16);
  *(uint32_t*)&o[(size_t)dst * H1 + c0] = ov;
}

// ---------- spmm2: wave-per-dst, 4 cols/lane, unroll-8 ----------
__global__ void spmm2_k(const ushort_t* __restrict__ pre, float* __restrict__ mu,
                        float* __restrict__ lv, float* __restrict__ zf,
                        ushort_t* __restrict__ zb,
                        const int* __restrict__ rs, const int* __restrict__ psrc,
                        const float* __restrict__ pw) {
  const int dst = blockIdx.x * 4 + (threadIdx.x >> 6);
  const int lane = threadIdx.x & 63;
  const int c0 = lane * 4;
  float a0 = 0.f, a1 = 0.f, a2 = 0.f, a3 = 0.f;
  if (dst < N_NODES) {
    const int s0 = rs[dst], e0 = rs[dst + 1];
    int i = s0;
    for (; i + 8 <= e0; i += 8) {
      int sr[8]; float wv[8]; uint2 v[8];
#pragma unroll
      for (int u = 0; u < 8; ++u) { sr[u] = psrc[i + u]; wv[u] = pw[i + u]; }
#pragma unroll
      for (int u = 0; u < 8; ++u) v[u] = *(const uint2*)&pre[(size_t)sr[u] * 256 + c0];
#pragma unroll
      for (int u = 0; u < 8; ++u) {
        a0 += wv[u] * b2f((ushort_t)(v[u].x & 0xffff));
        a1 += wv[u] * b2f((ushort_t)(v[u].x >> 16));
        a2 += wv[u] * b2f((ushort_t)(v[u].y & 0xffff));
        a3 += wv[u] * b2f((ushort_t)(v[u].y >> 16));
      }
    }
    for (; i < e0; ++i) {
      float wv = pw[i];
      uint2 v = *(const uint2*)&pre[(size_t)psrc[i] * 256 + c0];
      a0 += wv * b2f((ushort_t)(v.x & 0xffff));
      a1 += wv * b2f((ushort_t)(v.x >> 16));
      a2 += wv * b2f((ushort_t)(v.y & 0xffff));
      a3 += wv * b2f((ushort_t)(v.y >> 16));
    }
  }
  if (lane < 32) {
    uint2 zv;
    zv.x = (uint32_t)f2b(a0) | ((uint32_t)f2b(a1) << 16);
    zv.y = (uint32_t)f2b(a2) | ((uint32_t)f2b(a3) << 16);
    *(uint2*)&zb[(size_t)dst * 128 + c0] = zv;
    if (dst < N_NODES) {
      float4 m4; m4.x = a0; m4.y = a1; m4.z = a2; m4.w = a3;
      *(float4*)&mu[(size_t)dst * 128 + c0] = m4;
      *(float4*)&zf[(size_t)dst * 128 + c0] = m4;
    }
  } else if (dst < N_NODES) {
    float4 l4; l4.x = a0; l4.y = a1; l4.z = a2; l4.w = a3;
    *(float4*)&lv[(size_t)dst * 128 + (c0 - 128)] = l4;
  }
}

// ---------- host ----------
extern "C" void kernel_launch(void* const* d_in, const int* in_sizes, int n_in,
                              void* d_out, int out_size, void* d_ws, size_t ws_size,
                              hipStream_t stream) {
  (void)in_sizes; (void)n_in; (void)out_size; (void)ws_size;
  const float* x  = (const float*)d_in[0];
  const float* ew = (const float*)d_in[1];
  const float* W1 = (const float*)d_in[2];
  const float* W2 = (const float*)d_in[3];
  const float* W3 = (const float*)d_in[4];
  const float* fc_w[5] = {(const float*)d_in[5], (const float*)d_in[9],  (const float*)d_in[13], (const float*)d_in[17], (const float*)d_in[21]};
  const float* fc_b[5] = {(const float*)d_in[6], (const float*)d_in[10], (const float*)d_in[14], (const float*)d_in[18], (const float*)d_in[22]};
  const float* bn_g[4] = {(const float*)d_in[7], (const float*)d_in[11], (const float*)d_in[15], (const float*)d_in[19]};
  const float* bn_b[4] = {(const float*)d_in[8], (const float*)d_in[12], (const float*)d_in[16], (const float*)d_in[20]};
  const int* esrc = (const int*)d_in[23];
  const int* edst = (const int*)d_in[24];
  float* out = (float*)d_out;

  float* out_adj = out;
  float* out_mu  = out + (size_t)100000000;
  float* out_lv  = out + (size_t)101280000;
  float* out_z   = out + (size_t)102560000;
  float* out_xr  = out + (size_t)103840000;

  char* w = (char*)d_ws;
  size_t off = 0;
  auto alloc = [&](size_t bytes) { size_t o = off; off = (off + bytes + 255) & ~(size_t)255; return o; };
  int*      cnt  = (int*)(w + alloc(4 * N_NODES));
  int*      rs   = (int*)(w + alloc(4 * (N_NODES + 1)));
  int*      cur  = (int*)(w + alloc(4 * N_NODES));
  int*      psrc = (int*)(w + alloc(4 * E_EDGES));
  float*    pw   = (float*)(w + alloc(4 * E_EDGES));
  ushort_t* w1T  = (ushort_t*)(w + alloc((size_t)2 * 1024 * K1P));
  ushort_t* w23T = (ushort_t*)(w + alloc((size_t)2 * 256 * 1024));
  ushort_t* f1T  = (ushort_t*)(w + alloc((size_t)2 * 256 * 128));
  ushort_t* f2T  = (ushort_t*)(w + alloc((size_t)2 * 512 * 256));
  ushort_t* f3T  = (ushort_t*)(w + alloc((size_t)2 * 1024 * 512));
  ushort_t* f4T  = (ushort_t*)(w + alloc((size_t)2 * 2048 * 1024));
  ushort_t* f5T  = (ushort_t*)(w + alloc((size_t)2 * 3072 * 2048));
  ushort_t* xb   = (ushort_t*)(w + alloc((size_t)2 * MP * K1P));
  ushort_t* xw1b = (ushort_t*)(w + alloc((size_t)2 * MP * H1));
  ushort_t* h1b  = (ushort_t*)(w + alloc((size_t)2 * MP * H1));
  ushort_t* preb = (ushort_t*)(w + alloc((size_t)2 * MP * 256));
  ushort_t* zb   = (ushort_t*)(w + alloc((size_t)2 * MP * 128));
  ushort_t* act1 = xw1b;   // 10240 x 256
  ushort_t* act2 = xb;     // 10240 x 512
  ushort_t* act3 = h1b;    // 10240 x 1024
  ushort_t* act4 = xb;     // 10240 x 2048

  // ---- CSR build ----
  zero_k<<<(N_NODES + 255) / 256, 256, 0, stream>>>(cnt, N_NODES);
  count_k<<<(E_EDGES + 255) / 256, 256, 0, stream>>>(edst, cnt);
  scan_k<<<1, 256, 0, stream>>>(cnt, rs, cur);
  fill_k<<<(E_EDGES + 255) / 256, 256, 0, stream>>>(esrc, edst, ew, cur, psrc, pw);

  // ---- conversions ----
  conv_x_k<<<(MP * 376) / 256, 256, 0, stream>>>(x, xb);
  {
    SegPack P;
    int b0 = 0;
    auto mk = [&](const float* s, ushort_t* d, int K, int Nn, int Kp, int Np) {
      Seg sg; sg.src = s; sg.dst = d; sg.K = K; sg.Nn = Nn; sg.Kp = Kp; sg.Np = Np;
      sg.tilesN = Np / 32; sg.blk0 = b0;
      b0 += (Kp / 32) * (Np / 32);
      return sg;
    };
    P.s[0] = mk(W1,      w1T,                       D_IN, 1024, K1P,  1024);
    P.s[1] = mk(W2,      w23T,                      1024, 128,  1024, 128);
    P.s[2] = mk(W3,      w23T + (size_t)128 * 1024, 1024, 128,  1024, 128);
    P.s[3] = mk(fc_w[0], f1T,                       128,  256,  128,  256);
    P.s[4] = mk(fc_w[1], f2T,                       256,  512,  256,  512);
    P.s[5] = mk(fc_w[2], f3T,                       512,  1024, 512,  1024);
    P.s[6] = mk(fc_w[3], f4T,                       1024, 2048, 1024, 2048);
    P.s[7] = mk(fc_w[4], f5T,                       2048, 3000, 2048, 3072);
    conv_w_all_k<<<b0, 256, 0, stream>>>(P);
  }

  dim3 blk2(256);
  // ---- GEMM1: xb (MP x K1P) @ W1 -> xw1b bf16 (MP x 1024) ----
  gemm3<0><<<dim3(MP / 128, 1024 / 256), blk2, 0, stream>>>(xb, w1T, K1P, xw1b, 1024, MP, 1024, nullptr, nullptr, nullptr);
  // ---- spmm1 (L2-chunked, unroll-8) + relu -> h1b bf16 ----
  spmm1c_k<<<dim3(MP / 4, 8), blk2, 0, stream>>>(xw1b, h1b, rs, psrc, pw);
  // ---- GEMM2: h1b @ [W2|W3] -> preb bf16 (MP x 256) ----
  gemm_bt<0><<<dim3(MP / 128, 2), blk2, 0, stream>>>(h1b, w23T, 1024, preb, 256, MP, 256, nullptr, nullptr, nullptr);
  // ---- spmm2 (wave-per-dst, unroll-8) -> mu/logvar/z (f32) + zb bf16 ----
  spmm2_k<<<dim3(MP / 4), blk2, 0, stream>>>(preb, out_mu, out_lv, out_z, zb, rs, psrc, pw);
  // ---- adj = z @ z^T (f32, symmetric transposed float4 store) ----
  gemm3<4><<<dim3(MP / 128, MP / 256), blk2, 0, stream>>>(zb, zb, 128, out_adj, 10000, N_NODES, N_NODES, nullptr, nullptr, nullptr);
  // ---- FC stack ----
  gemm_bt<1><<<dim3(MP / 128, 2), blk2, 0, stream>>>(zb,   f1T, 128,  act1, 256,  MP, 256,  fc_b[0], bn_g[0], bn_b[0]);
  gemm_bt<1><<<dim3(MP / 128, 4), blk2, 0, stream>>>(act1, f2T, 256,  act2, 512,  MP, 512,  fc_b[1], bn_g[1], bn_b[1]);
  gemm3<1><<<dim3(MP / 128, 1024 / 256), blk2, 0, stream>>>(act2, f3T, 512,  act3, 1024, MP, 1024, fc_b[2], bn_g[2], bn_b[2]);
  gemm3<1><<<dim3(MP / 128, 2048 / 256), blk2, 0, stream>>>(act3, f4T, 1024, act4, 2048, MP, 2048, fc_b[3], bn_g[3], bn_b[3]);
  gemm3<2><<<dim3(MP / 128, 3072 / 256), blk2, 0, stream>>>(act4, f5T, 2048, out_xr, 3000, N_NODES, 3000, fc_b[4], nullptr, nullptr);
}

// Round 15
// 803.928 us; speedup vs baseline: 2.4314x; 2.4314x over previous
//
#include <hip/hip_runtime.h>
#include <stdint.h>

typedef unsigned short ushort_t;
typedef __attribute__((ext_vector_type(8))) short short8;
typedef __attribute__((ext_vector_type(4))) float f32x4;

#define N_NODES 10000
#define MP      10240      // 80 * 128
#define E_EDGES 320000
#define D_IN    3000
#define K1P     3008       // 94 * 32
#define H1      1024
#define H2      128

// ---------- bf16 helpers ----------
static __device__ __forceinline__ float b2f(ushort_t u) {
  union { uint32_t u; float f; } x; x.u = ((uint32_t)u) << 16; return x.f;
}
static __device__ __forceinline__ ushort_t f2b(float f) {
  union { float f; uint32_t u; } x; x.f = f;
  uint32_t r = x.u + 0x7FFF + ((x.u >> 16) & 1);
  return (ushort_t)(r >> 16);
}

// ---------- async global->LDS (16B per lane) ----------
static __device__ __forceinline__ void gload16(const void* g, void* l) {
  __builtin_amdgcn_global_load_lds(
      (const __attribute__((address_space(1))) uint32_t*)g,
      (__attribute__((address_space(3))) uint32_t*)l, 16, 0, 0);
}

// ---------- CSR build ----------
__global__ void zero_k(int* p, int n) {
  int i = blockIdx.x * 256 + threadIdx.x;
  if (i < n) p[i] = 0;
}
__global__ void count_k(const int* __restrict__ ed, int* __restrict__ cnt) {
  int e = blockIdx.x * 256 + threadIdx.x;
  if (e < E_EDGES) atomicAdd(&cnt[ed[e]], 1);
}
__global__ void scan_k(const int* __restrict__ cnt, int* __restrict__ rs, int* __restrict__ cur) {
  __shared__ int sums[256];
  int t = threadIdx.x;
  const int per = 40;
  int base = t * per;
  int s = 0;
  for (int i = 0; i < per; i++) { int idx = base + i; if (idx < N_NODES) s += cnt[idx]; }
  sums[t] = s;
  __syncthreads();
  if (t == 0) { int run = 0; for (int i = 0; i < 256; i++) { int v = sums[i]; sums[i] = run; run += v; } }
  __syncthreads();
  int run = sums[t];
  for (int i = 0; i < per; i++) {
    int idx = base + i;
    if (idx < N_NODES) { rs[idx] = run; cur[idx] = run; run += cnt[idx]; }
  }
  if (t == 255) rs[N_NODES] = run;
}
__global__ void fill_k(const int* __restrict__ es, const int* __restrict__ ed,
                       const float* __restrict__ ew,
                       int* __restrict__ cur, int* __restrict__ psrc, float* __restrict__ pw) {
  int e = blockIdx.x * 256 + threadIdx.x;
  if (e >= E_EDGES) return;
  int d = ed[e];
  int pos = atomicAdd(&cur[d], 1);
  psrc[pos] = es[e];
  pw[pos] = ew[e];
}

// ---------- x conversion ----------
__global__ void conv_x_k(const float* __restrict__ x, ushort_t* __restrict__ xb) {
  int g = blockIdx.x * 256 + threadIdx.x;
  int row = g / 376;
  int c8 = (g % 376) * 8;
  float v[8];
  if (row < N_NODES && c8 < 3000) {
    const float4 f0 = *(const float4*)(x + (size_t)row * 3000 + c8);
    const float4 f1 = *(const float4*)(x + (size_t)row * 3000 + c8 + 4);
    v[0]=f0.x; v[1]=f0.y; v[2]=f0.z; v[3]=f0.w;
    v[4]=f1.x; v[5]=f1.y; v[6]=f1.z; v[7]=f1.w;
  } else {
#pragma unroll
    for (int i = 0; i < 8; i++) v[i] = 0.f;
  }
  uint32_t o0 = (uint32_t)f2b(v[0]) | ((uint32_t)f2b(v[1]) << 16);
  uint32_t o1 = (uint32_t)f2b(v[2]) | ((uint32_t)f2b(v[3]) << 16);
  uint32_t o2 = (uint32_t)f2b(v[4]) | ((uint32_t)f2b(v[5]) << 16);
  uint32_t o3 = (uint32_t)f2b(v[6]) | ((uint32_t)f2b(v[7]) << 16);
  uint4 ov; ov.x=o0; ov.y=o1; ov.z=o2; ov.w=o3;
  *(uint4*)&xb[(size_t)row * K1P + c8] = ov;
}

// ---------- fused weight transpose+convert ----------
struct Seg { const float* src; ushort_t* dst; int K, Nn, Kp, Np, tilesN, blk0; };
struct SegPack { Seg s[8]; };
__global__ void conv_w_all_k(SegPack P) {
  __shared__ float tile[32][33];
  int b = blockIdx.x;
  int si = 0;
#pragma unroll
  for (int i = 1; i < 8; ++i) if (b >= P.s[i].blk0) si = i;
  Seg sg = P.s[si];
  int rel = b - sg.blk0;
  int tk = rel / sg.tilesN, tn = rel % sg.tilesN;
  int tx = threadIdx.x & 31, ty0 = threadIdx.x >> 5;
#pragma unroll
  for (int i = 0; i < 4; ++i) {
    int ty = ty0 + i * 8;
    int k = tk * 32 + ty, n = tn * 32 + tx;
    tile[ty][tx] = (k < sg.K && n < sg.Nn) ? sg.src[(size_t)k * sg.Nn + n] : 0.f;
  }
  __syncthreads();
#pragma unroll
  for (int i = 0; i < 4; ++i) {
    int ty = ty0 + i * 8;
    int n = tn * 32 + ty, k = tk * 32 + tx;
    sg.dst[(size_t)n * sg.Kp + k] = f2b(tile[tx][ty]);
  }
}

// ---------- small 128x128 GEMM (tiny GEMMs only) ----------
template<int EPI>
__global__ __launch_bounds__(256)
void gemm_bt(const ushort_t* __restrict__ A, const ushort_t* __restrict__ BT, int K,
             void* __restrict__ outp, int ldOut, int realM, int realN,
             const float* __restrict__ bias, const float* __restrict__ bng,
             const float* __restrict__ bnb)
{
  __shared__ ushort_t lA[128 * 32];
  __shared__ ushort_t lB[128 * 32];
  const int tid  = threadIdx.x;
  const int row0 = blockIdx.x * 128;
  const int col0 = blockIdx.y * 128;
  const int lane = tid & 63;
  const int wave = tid >> 6;
  const int wr = (wave >> 1) * 64, wc = (wave & 1) * 64;
  const int fr = lane & 15, fq = lane >> 4;

  f32x4 acc[4][4] = {};

  const int rA = tid >> 2;
  const int cA = (tid & 3) * 8;
  const ushort_t* Ab = A  + (size_t)(row0 + rA) * K + cA;
  const ushort_t* Bb = BT + (size_t)(col0 + rA) * K + cA;
  ushort_t* lA0 = &lA[tid * 8];
  ushort_t* lA1 = &lA[2048 + tid * 8];
  ushort_t* lB0 = &lB[tid * 8];
  ushort_t* lB1 = &lB[2048 + tid * 8];
  const size_t rstep = (size_t)64 * K;

  for (int k0 = 0; k0 < K; k0 += 32) {
    gload16(Ab + k0,         lA0);
    gload16(Ab + rstep + k0, lA1);
    gload16(Bb + k0,         lB0);
    gload16(Bb + rstep + k0, lB1);
    __syncthreads();
    short8 af[4], bv[4];
#pragma unroll
    for (int m = 0; m < 4; m++) af[m] = *(const short8*)&lA[(wr + m * 16 + fr) * 32 + fq * 8];
#pragma unroll
    for (int n = 0; n < 4; n++) bv[n] = *(const short8*)&lB[(wc + n * 16 + fr) * 32 + fq * 8];
#pragma unroll
    for (int m = 0; m < 4; m++)
#pragma unroll
      for (int n = 0; n < 4; n++)
        acc[m][n] = __builtin_amdgcn_mfma_f32_16x16x32_bf16(af[m], bv[n], acc[m][n], 0, 0, 0);
    __syncthreads();
  }

  const float inv = 0.9999950000374997f;
#pragma unroll
  for (int n = 0; n < 4; n++) {
    int col = col0 + wc + n * 16 + fr;
    float s = 0.f, t = 0.f, bb = 0.f;
    if (EPI == 1) { s = inv * bng[col]; t = bias[col] * s + bnb[col]; }
    if (EPI == 2) { bb = (col < realN) ? bias[col] : 0.f; }
#pragma unroll
    for (int m = 0; m < 4; m++) {
      int rowb = row0 + wr + m * 16 + fq * 4;
#pragma unroll
      for (int r = 0; r < 4; r++) {
        int row = rowb + r;
        float v = acc[m][n][r];
        if (EPI == 0) {
          ((ushort_t*)outp)[(size_t)row * ldOut + col] = f2b(v);
        } else if (EPI == 1) {
          v = fmaxf(v * s + t, 0.f);
          ((ushort_t*)outp)[(size_t)row * ldOut + col] = f2b(v);
        } else if (EPI == 2) {
          if (row < realM && col < realN)
            ((float*)outp)[(size_t)row * ldOut + col] = v + bb;
        } else {
          if (row < realM && col < realN)
            ((float*)outp)[(size_t)row * ldOut + col] = v;
        }
      }
    }
  }
}

// ---------- gemm3: 128x256 tile, 4 waves, per-wave 128x64 (MR=8,NR=4), BK=32,
// 3 LDS bufs, depth-2 prefetch, ONE barrier + ONE counted vmcnt(6) per K-tile.
// Row-major XCD-chunk traversal for A-panel L2 reuse.
// EPI 0: bf16 plain; 1: bf16 relu((v+b)*inv*g+be); 2: f32 v+bias guarded;
// 3: f32 plain guarded (64B-sector-aligned scalar stores — used for adj: the
//    transposed float4 variant quarter-fills 64B sectors -> 3.9x write amp).
template<int EPI>
__global__ __launch_bounds__(256, 2)
void gemm3(const ushort_t* __restrict__ A, const ushort_t* __restrict__ BT, int K,
           void* __restrict__ outp, int ldOut, int realM, int realN,
           const float* __restrict__ bias, const float* __restrict__ bng,
           const float* __restrict__ bnb)
{
  __shared__ ushort_t lA[3 * 128 * 32];
  __shared__ ushort_t lB[3 * 256 * 32];
  const int tid = threadIdx.x;
  const int wn  = tid >> 6;                 // 4 waves split N
  const int fr  = tid & 15, fq = (tid >> 4) & 3;

  int gy = gridDim.y;                        // # of 256-col tiles
  int nwg = gridDim.x * gy;
  int bid = blockIdx.y * gridDim.x + blockIdx.x;
  int q8 = nwg >> 3, r8 = nwg & 7;
  int xcd = bid & 7, j = bid >> 3;
  int swz = (xcd < r8 ? xcd * (q8 + 1) : r8 * (q8 + 1) + (xcd - r8) * q8) + j;
  const int row0 = (swz / gy) * 128;         // row-major: col fastest
  const int col0 = (swz % gy) * 256;

  f32x4 acc[8][4] = {};

  auto stA = [&](int p, int kt, int r) {
    int c = r * 256 + tid;
    int row = c >> 2, slot = c & 3;
    int ss = slot ^ ((row >> 1) & 3);              // pre-swizzled SOURCE
    gload16(A + (size_t)(row0 + row) * K + kt * 32 + ss * 8,
            &lA[p * (128 * 32) + c * 8]);          // linear LDS dest
  };
  auto stB = [&](int p, int kt, int r) {
    int c = r * 256 + tid;
    int row = c >> 2, slot = c & 3;
    int ss = slot ^ ((row >> 1) & 3);
    gload16(BT + (size_t)(col0 + row) * K + kt * 32 + ss * 8,
            &lB[p * (256 * 32) + c * 8]);
  };
  auto stage = [&](int p, int kt) {
    stA(p, kt, 0); stA(p, kt, 1);
    stB(p, kt, 0); stB(p, kt, 1); stB(p, kt, 2); stB(p, kt, 3);
  };

  const int NT = K >> 5;                    // requires NT >= 2 (all uses: >= 4)
  stage(0, 0);
  stage(1, 1);

  for (int t = 0; t < NT; ++t) {
    const int p = t % 3;
    const int s = (t + 2) % 3;              // buffer of tile t-1, reads done pre-barrier
    const int ts = (t + 2 < NT) ? t + 2 : NT - 1;  // clamped dummy restage on tail
    // outstanding here = tiles t, t+1 (12 loads); drain exactly tile t
    asm volatile("s_waitcnt vmcnt(6)" ::: "memory");
    __builtin_amdgcn_s_barrier();
    asm volatile("" ::: "memory");
    stage(s, ts);

    short8 bf[4], af[8];
#pragma unroll
    for (int n = 0; n < 4; ++n) {
      int rb = wn * 64 + n * 16 + fr;
      bf[n] = *(const short8*)&lB[p * (256 * 32) + rb * 32 + ((fq ^ ((rb >> 1) & 3)) * 8)];
    }
#pragma unroll
    for (int m = 0; m < 8; ++m) {
      int ra = m * 16 + fr;
      af[m] = *(const short8*)&lA[p * (128 * 32) + ra * 32 + ((fq ^ ((ra >> 1) & 3)) * 8)];
    }
    __builtin_amdgcn_s_setprio(1);
#pragma unroll
    for (int m = 0; m < 8; ++m)
#pragma unroll
      for (int n = 0; n < 4; ++n)
        acc[m][n] = __builtin_amdgcn_mfma_f32_16x16x32_bf16(af[m], bf[n], acc[m][n], 0, 0, 0);
    __builtin_amdgcn_s_setprio(0);
    asm volatile("" ::: "memory");
  }

  const float inv = 0.9999950000374997f;
#pragma unroll
  for (int n = 0; n < 4; ++n) {
    int col = col0 + wn * 64 + n * 16 + fr;
    float sc = 0.f, tc = 0.f, bb = 0.f;
    if (EPI == 1) { sc = inv * bng[col]; tc = bias[col] * sc + bnb[col]; }
    if (EPI == 2) { bb = (col < realN) ? bias[col] : 0.f; }
#pragma unroll
    for (int m = 0; m < 8; ++m) {
      int rowb = row0 + m * 16 + fq * 4;
#pragma unroll
      for (int r = 0; r < 4; ++r) {
        int row = rowb + r;
        float v = acc[m][n][r];
        if (EPI == 0) {
          ((ushort_t*)outp)[(size_t)row * ldOut + col] = f2b(v);
        } else if (EPI == 1) {
          v = fmaxf(v * sc + tc, 0.f);
          ((ushort_t*)outp)[(size_t)row * ldOut + col] = f2b(v);
        } else if (EPI == 2) {
          if (row < realM && col < realN)
            ((float*)outp)[(size_t)row * ldOut + col] = v + bb;
        } else if (EPI == 3) {
          if (row < realM && col < realN)
            ((float*)outp)[(size_t)row * ldOut + col] = v;
        }
      }
    }
  }
}

// ---------- spmm1 L2-chunked + unroll-8 gather ----------
__global__ void spmm1c_k(const ushort_t* __restrict__ h, ushort_t* __restrict__ o,
                         const int* __restrict__ rs, const int* __restrict__ psrc,
                         const float* __restrict__ pw) {
  const int chunk = blockIdx.y;
  const int dst = blockIdx.x * 4 + (threadIdx.x >> 6);
  const int lane = threadIdx.x & 63;
  const int c0 = chunk * 128 + lane * 2;
  float a0 = 0.f, a1 = 0.f;
  if (dst < N_NODES) {
    const int s0 = rs[dst], e0 = rs[dst + 1];
    int i = s0;
    for (; i + 8 <= e0; i += 8) {
      int   sr[8]; float wv[8]; uint32_t v[8];
#pragma unroll
      for (int u = 0; u < 8; ++u) { sr[u] = psrc[i + u]; wv[u] = pw[i + u]; }
#pragma unroll
      for (int u = 0; u < 8; ++u) v[u] = *(const uint32_t*)&h[(size_t)sr[u] * H1 + c0];
#pragma unroll
      for (int u = 0; u < 8; ++u) {
        a0 += wv[u] * b2f((ushort_t)(v[u] & 0xffff));
        a1 += wv[u] * b2f((ushort_t)(v[u] >> 16));
      }
    }
    for (; i < e0; ++i) {
      float wv = pw[i];
      uint32_t v = *(const uint32_t*)&h[(size_t)psrc[i] * H1 + c0];
      a0 += wv * b2f((ushort_t)(v & 0xffff));
      a1 += wv * b2f((ushort_t)(v >> 16));
    }
  }
  uint32_t ov = (uint32_t)f2b(fmaxf(a0, 0.f)) | ((uint32_t)f2b(fmaxf(a1, 0.f)) << 16);
  *(uint32_t*)&o[(size_t)dst * H1 + c0] = ov;
}

// ---------- spmm2: wave-per-dst, 4 cols/lane, unroll-8 ----------
__global__ void spmm2_k(const ushort_t* __restrict__ pre, float* __restrict__ mu,
                        float* __restrict__ lv, float* __restrict__ zf,
                        ushort_t* __restrict__ zb,
                        const int* __restrict__ rs, const int* __restrict__ psrc,
                        const float* __restrict__ pw) {
  const int dst = blockIdx.x * 4 + (threadIdx.x >> 6);
  const int lane = threadIdx.x & 63;
  const int c0 = lane * 4;
  float a0 = 0.f, a1 = 0.f, a2 = 0.f, a3 = 0.f;
  if (dst < N_NODES) {
    const int s0 = rs[dst], e0 = rs[dst + 1];
    int i = s0;
    for (; i + 8 <= e0; i += 8) {
      int sr[8]; float wv[8]; uint2 v[8];
#pragma unroll
      for (int u = 0; u < 8; ++u) { sr[u] = psrc[i + u]; wv[u] = pw[i + u]; }
#pragma unroll
      for (int u = 0; u < 8; ++u) v[u] = *(const uint2*)&pre[(size_t)sr[u] * 256 + c0];
#pragma unroll
      for (int u = 0; u < 8; ++u) {
        a0 += wv[u] * b2f((ushort_t)(v[u].x & 0xffff));
        a1 += wv[u] * b2f((ushort_t)(v[u].x >> 16));
        a2 += wv[u] * b2f((ushort_t)(v[u].y & 0xffff));
        a3 += wv[u] * b2f((ushort_t)(v[u].y >> 16));
      }
    }
    for (; i < e0; ++i) {
      float wv = pw[i];
      uint2 v = *(const uint2*)&pre[(size_t)psrc[i] * 256 + c0];
      a0 += wv * b2f((ushort_t)(v.x & 0xffff));
      a1 += wv * b2f((ushort_t)(v.x >> 16));
      a2 += wv * b2f((ushort_t)(v.y & 0xffff));
      a3 += wv * b2f((ushort_t)(v.y >> 16));
    }
  }
  if (lane < 32) {
    uint2 zv;
    zv.x = (uint32_t)f2b(a0) | ((uint32_t)f2b(a1) << 16);
    zv.y = (uint32_t)f2b(a2) | ((uint32_t)f2b(a3) << 16);
    *(uint2*)&zb[(size_t)dst * 128 + c0] = zv;
    if (dst < N_NODES) {
      float4 m4; m4.x = a0; m4.y = a1; m4.z = a2; m4.w = a3;
      *(float4*)&mu[(size_t)dst * 128 + c0] = m4;
      *(float4*)&zf[(size_t)dst * 128 + c0] = m4;
    }
  } else if (dst < N_NODES) {
    float4 l4; l4.x = a0; l4.y = a1; l4.z = a2; l4.w = a3;
    *(float4*)&lv[(size_t)dst * 128 + (c0 - 128)] = l4;
  }
}

// ---------- host ----------
extern "C" void kernel_launch(void* const* d_in, const int* in_sizes, int n_in,
                              void* d_out, int out_size, void* d_ws, size_t ws_size,
                              hipStream_t stream) {
  (void)in_sizes; (void)n_in; (void)out_size; (void)ws_size;
  const float* x  = (const float*)d_in[0];
  const float* ew = (const float*)d_in[1];
  const float* W1 = (const float*)d_in[2];
  const float* W2 = (const float*)d_in[3];
  const float* W3 = (const float*)d_in[4];
  const float* fc_w[5] = {(const float*)d_in[5], (const float*)d_in[9],  (const float*)d_in[13], (const float*)d_in[17], (const float*)d_in[21]};
  const float* fc_b[5] = {(const float*)d_in[6], (const float*)d_in[10], (const float*)d_in[14], (const float*)d_in[18], (const float*)d_in[22]};
  const float* bn_g[4] = {(const float*)d_in[7], (const float*)d_in[11], (const float*)d_in[15], (const float*)d_in[19]};
  const float* bn_b[4] = {(const float*)d_in[8], (const float*)d_in[12], (const float*)d_in[16], (const float*)d_in[20]};
  const int* esrc = (const int*)d_in[23];
  const int* edst = (const int*)d_in[24];
  float* out = (float*)d_out;

  float* out_adj = out;
  float* out_mu  = out + (size_t)100000000;
  float* out_lv  = out + (size_t)101280000;
  float* out_z   = out + (size_t)102560000;
  float* out_xr  = out + (size_t)103840000;

  char* w = (char*)d_ws;
  size_t off = 0;
  auto alloc = [&](size_t bytes) { size_t o = off; off = (off + bytes + 255) & ~(size_t)255; return o; };
  int*      cnt  = (int*)(w + alloc(4 * N_NODES));
  int*      rs   = (int*)(w + alloc(4 * (N_NODES + 1)));
  int*      cur  = (int*)(w + alloc(4 * N_NODES));
  int*      psrc = (int*)(w + alloc(4 * E_EDGES));
  float*    pw   = (float*)(w + alloc(4 * E_EDGES));
  ushort_t* w1T  = (ushort_t*)(w + alloc((size_t)2 * 1024 * K1P));
  ushort_t* w23T = (ushort_t*)(w + alloc((size_t)2 * 256 * 1024));
  ushort_t* f1T  = (ushort_t*)(w + alloc((size_t)2 * 256 * 128));
  ushort_t* f2T  = (ushort_t*)(w + alloc((size_t)2 * 512 * 256));
  ushort_t* f3T  = (ushort_t*)(w + alloc((size_t)2 * 1024 * 512));
  ushort_t* f4T  = (ushort_t*)(w + alloc((size_t)2 * 2048 * 1024));
  ushort_t* f5T  = (ushort_t*)(w + alloc((size_t)2 * 3072 * 2048));
  ushort_t* xb   = (ushort_t*)(w + alloc((size_t)2 * MP * K1P));
  ushort_t* xw1b = (ushort_t*)(w + alloc((size_t)2 * MP * H1));
  ushort_t* h1b  = (ushort_t*)(w + alloc((size_t)2 * MP * H1));
  ushort_t* preb = (ushort_t*)(w + alloc((size_t)2 * MP * 256));
  ushort_t* zb   = (ushort_t*)(w + alloc((size_t)2 * MP * 128));
  ushort_t* act1 = xw1b;   // 10240 x 256
  ushort_t* act2 = xb;     // 10240 x 512
  ushort_t* act3 = h1b;    // 10240 x 1024
  ushort_t* act4 = xb;     // 10240 x 2048

  // ---- CSR build ----
  zero_k<<<(N_NODES + 255) / 256, 256, 0, stream>>>(cnt, N_NODES);
  count_k<<<(E_EDGES + 255) / 256, 256, 0, stream>>>(edst, cnt);
  scan_k<<<1, 256, 0, stream>>>(cnt, rs, cur);
  fill_k<<<(E_EDGES + 255) / 256, 256, 0, stream>>>(esrc, edst, ew, cur, psrc, pw);

  // ---- conversions ----
  conv_x_k<<<(MP * 376) / 256, 256, 0, stream>>>(x, xb);
  {
    SegPack P;
    int b0 = 0;
    auto mk = [&](const float* s, ushort_t* d, int K, int Nn, int Kp, int Np) {
      Seg sg; sg.src = s; sg.dst = d; sg.K = K; sg.Nn = Nn; sg.Kp = Kp; sg.Np = Np;
      sg.tilesN = Np / 32; sg.blk0 = b0;
      b0 += (Kp / 32) * (Np / 32);
      return sg;
    };
    P.s[0] = mk(W1,      w1T,                       D_IN, 1024, K1P,  1024);
    P.s[1] = mk(W2,      w23T,                      1024, 128,  1024, 128);
    P.s[2] = mk(W3,      w23T + (size_t)128 * 1024, 1024, 128,  1024, 128);
    P.s[3] = mk(fc_w[0], f1T,                       128,  256,  128,  256);
    P.s[4] = mk(fc_w[1], f2T,                       256,  512,  256,  512);
    P.s[5] = mk(fc_w[2], f3T,                       512,  1024, 512,  1024);
    P.s[6] = mk(fc_w[3], f4T,                       1024, 2048, 1024, 2048);
    P.s[7] = mk(fc_w[4], f5T,                       2048, 3000, 2048, 3072);
    conv_w_all_k<<<b0, 256, 0, stream>>>(P);
  }

  dim3 blk2(256);
  // ---- GEMM1: xb (MP x K1P) @ W1 -> xw1b bf16 (MP x 1024) ----
  gemm3<0><<<dim3(MP / 128, 1024 / 256), blk2, 0, stream>>>(xb, w1T, K1P, xw1b, 1024, MP, 1024, nullptr, nullptr, nullptr);
  // ---- spmm1 (L2-chunked, unroll-8) + relu -> h1b bf16 ----
  spmm1c_k<<<dim3(MP / 4, 8), blk2, 0, stream>>>(xw1b, h1b, rs, psrc, pw);
  // ---- GEMM2: h1b @ [W2|W3] -> preb bf16 (MP x 256) ----
  gemm_bt<0><<<dim3(MP / 128, 2), blk2, 0, stream>>>(h1b, w23T, 1024, preb, 256, MP, 256, nullptr, nullptr, nullptr);
  // ---- spmm2 (wave-per-dst, unroll-8) -> mu/logvar/z (f32) + zb bf16 ----
  spmm2_k<<<dim3(MP / 4), blk2, 0, stream>>>(preb, out_mu, out_lv, out_z, zb, rs, psrc, pw);
  // ---- adj = z @ z^T (f32, plain guarded scalar stores: full 64B sectors) ----
  gemm3<3><<<dim3(MP / 128, MP / 256), blk2, 0, stream>>>(zb, zb, 128, out_adj, 10000, N_NODES, N_NODES, nullptr, nullptr, nullptr);
  // ---- FC stack ----
  gemm_bt<1><<<dim3(MP / 128, 2), blk2, 0, stream>>>(zb,   f1T, 128,  act1, 256,  MP, 256,  fc_b[0], bn_g[0], bn_b[0]);
  gemm_bt<1><<<dim3(MP / 128, 4), blk2, 0, stream>>>(act1, f2T, 256,  act2, 512,  MP, 512,  fc_b[1], bn_g[1], bn_b[1]);
  gemm3<1><<<dim3(MP / 128, 1024 / 256), blk2, 0, stream>>>(act2, f3T, 512,  act3, 1024, MP, 1024, fc_b[2], bn_g[2], bn_b[2]);
  gemm3<1><<<dim3(MP / 128, 2048 / 256), blk2, 0, stream>>>(act3, f4T, 1024, act4, 2048, MP, 2048, fc_b[3], bn_g[3], bn_b[3]);
  gemm3<2><<<dim3(MP / 128, 3072 / 256), blk2, 0, stream>>>(act4, f5T, 2048, out_xr, 3000, N_NODES, 3000, fc_b[4], nullptr, nullptr);
}

// Round 16
// 786.751 us; speedup vs baseline: 2.4845x; 1.0218x over previous
//
#include <hip/hip_runtime.h>
#include <stdint.h>

typedef unsigned short ushort_t;
typedef __attribute__((ext_vector_type(8))) short short8;
typedef __attribute__((ext_vector_type(4))) float f32x4;

#define N_NODES 10000
#define MP      10240      // 80 * 128
#define E_EDGES 320000
#define D_IN    3000
#define K1P     3008       // 94 * 32
#define H1      1024
#define H2      128

// ---------- bf16 helpers ----------
static __device__ __forceinline__ float b2f(ushort_t u) {
  union { uint32_t u; float f; } x; x.u = ((uint32_t)u) << 16; return x.f;
}
static __device__ __forceinline__ ushort_t f2b(float f) {
  union { float f; uint32_t u; } x; x.f = f;
  uint32_t r = x.u + 0x7FFF + ((x.u >> 16) & 1);
  return (ushort_t)(r >> 16);
}

// ---------- async global->LDS (16B per lane) ----------
static __device__ __forceinline__ void gload16(const void* g, void* l) {
  __builtin_amdgcn_global_load_lds(
      (const __attribute__((address_space(1))) uint32_t*)g,
      (__attribute__((address_space(3))) uint32_t*)l, 16, 0, 0);
}

// ---------- CSR build ----------
__global__ void zero_k(int* p, int n) {
  int i = blockIdx.x * 256 + threadIdx.x;
  if (i < n) p[i] = 0;
}
__global__ void count_k(const int* __restrict__ ed, int* __restrict__ cnt) {
  int e = blockIdx.x * 256 + threadIdx.x;
  if (e < E_EDGES) atomicAdd(&cnt[ed[e]], 1);
}
__global__ void scan_k(const int* __restrict__ cnt, int* __restrict__ rs, int* __restrict__ cur) {
  __shared__ int sums[256];
  int t = threadIdx.x;
  const int per = 40;
  int base = t * per;
  int s = 0;
  for (int i = 0; i < per; i++) { int idx = base + i; if (idx < N_NODES) s += cnt[idx]; }
  sums[t] = s;
  __syncthreads();
  if (t == 0) { int run = 0; for (int i = 0; i < 256; i++) { int v = sums[i]; sums[i] = run; run += v; } }
  __syncthreads();
  int run = sums[t];
  for (int i = 0; i < per; i++) {
    int idx = base + i;
    if (idx < N_NODES) { rs[idx] = run; cur[idx] = run; run += cnt[idx]; }
  }
  if (t == 255) rs[N_NODES] = run;
}
__global__ void fill_k(const int* __restrict__ es, const int* __restrict__ ed,
                       const float* __restrict__ ew,
                       int* __restrict__ cur, int* __restrict__ psrc, float* __restrict__ pw) {
  int e = blockIdx.x * 256 + threadIdx.x;
  if (e >= E_EDGES) return;
  int d = ed[e];
  int pos = atomicAdd(&cur[d], 1);
  psrc[pos] = es[e];
  pw[pos] = ew[e];
}

// ---------- x conversion ----------
__global__ void conv_x_k(const float* __restrict__ x, ushort_t* __restrict__ xb) {
  int g = blockIdx.x * 256 + threadIdx.x;
  int row = g / 376;
  int c8 = (g % 376) * 8;
  float v[8];
  if (row < N_NODES && c8 < 3000) {
    const float4 f0 = *(const float4*)(x + (size_t)row * 3000 + c8);
    const float4 f1 = *(const float4*)(x + (size_t)row * 3000 + c8 + 4);
    v[0]=f0.x; v[1]=f0.y; v[2]=f0.z; v[3]=f0.w;
    v[4]=f1.x; v[5]=f1.y; v[6]=f1.z; v[7]=f1.w;
  } else {
#pragma unroll
    for (int i = 0; i < 8; i++) v[i] = 0.f;
  }
  uint32_t o0 = (uint32_t)f2b(v[0]) | ((uint32_t)f2b(v[1]) << 16);
  uint32_t o1 = (uint32_t)f2b(v[2]) | ((uint32_t)f2b(v[3]) << 16);
  uint32_t o2 = (uint32_t)f2b(v[4]) | ((uint32_t)f2b(v[5]) << 16);
  uint32_t o3 = (uint32_t)f2b(v[6]) | ((uint32_t)f2b(v[7]) << 16);
  uint4 ov; ov.x=o0; ov.y=o1; ov.z=o2; ov.w=o3;
  *(uint4*)&xb[(size_t)row * K1P + c8] = ov;
}

// ---------- fused weight transpose+convert ----------
struct Seg { const float* src; ushort_t* dst; int K, Nn, Kp, Np, tilesN, blk0; };
struct SegPack { Seg s[8]; };
__global__ void conv_w_all_k(SegPack P) {
  __shared__ float tile[32][33];
  int b = blockIdx.x;
  int si = 0;
#pragma unroll
  for (int i = 1; i < 8; ++i) if (b >= P.s[i].blk0) si = i;
  Seg sg = P.s[si];
  int rel = b - sg.blk0;
  int tk = rel / sg.tilesN, tn = rel % sg.tilesN;
  int tx = threadIdx.x & 31, ty0 = threadIdx.x >> 5;
#pragma unroll
  for (int i = 0; i < 4; ++i) {
    int ty = ty0 + i * 8;
    int k = tk * 32 + ty, n = tn * 32 + tx;
    tile[ty][tx] = (k < sg.K && n < sg.Nn) ? sg.src[(size_t)k * sg.Nn + n] : 0.f;
  }
  __syncthreads();
#pragma unroll
  for (int i = 0; i < 4; ++i) {
    int ty = ty0 + i * 8;
    int n = tn * 32 + ty, k = tk * 32 + tx;
    sg.dst[(size_t)n * sg.Kp + k] = f2b(tile[tx][ty]);
  }
}

// ---------- small 128x128 GEMM (tiny GEMMs only) ----------
template<int EPI>
__global__ __launch_bounds__(256)
void gemm_bt(const ushort_t* __restrict__ A, const ushort_t* __restrict__ BT, int K,
             void* __restrict__ outp, int ldOut, int realM, int realN,
             const float* __restrict__ bias, const float* __restrict__ bng,
             const float* __restrict__ bnb)
{
  __shared__ ushort_t lA[128 * 32];
  __shared__ ushort_t lB[128 * 32];
  const int tid  = threadIdx.x;
  const int row0 = blockIdx.x * 128;
  const int col0 = blockIdx.y * 128;
  const int lane = tid & 63;
  const int wave = tid >> 6;
  const int wr = (wave >> 1) * 64, wc = (wave & 1) * 64;
  const int fr = lane & 15, fq = lane >> 4;

  f32x4 acc[4][4] = {};

  const int rA = tid >> 2;
  const int cA = (tid & 3) * 8;
  const ushort_t* Ab = A  + (size_t)(row0 + rA) * K + cA;
  const ushort_t* Bb = BT + (size_t)(col0 + rA) * K + cA;
  ushort_t* lA0 = &lA[tid * 8];
  ushort_t* lA1 = &lA[2048 + tid * 8];
  ushort_t* lB0 = &lB[tid * 8];
  ushort_t* lB1 = &lB[2048 + tid * 8];
  const size_t rstep = (size_t)64 * K;

  for (int k0 = 0; k0 < K; k0 += 32) {
    gload16(Ab + k0,         lA0);
    gload16(Ab + rstep + k0, lA1);
    gload16(Bb + k0,         lB0);
    gload16(Bb + rstep + k0, lB1);
    __syncthreads();
    short8 af[4], bv[4];
#pragma unroll
    for (int m = 0; m < 4; m++) af[m] = *(const short8*)&lA[(wr + m * 16 + fr) * 32 + fq * 8];
#pragma unroll
    for (int n = 0; n < 4; n++) bv[n] = *(const short8*)&lB[(wc + n * 16 + fr) * 32 + fq * 8];
#pragma unroll
    for (int m = 0; m < 4; m++)
#pragma unroll
      for (int n = 0; n < 4; n++)
        acc[m][n] = __builtin_amdgcn_mfma_f32_16x16x32_bf16(af[m], bv[n], acc[m][n], 0, 0, 0);
    __syncthreads();
  }

  const float inv = 0.9999950000374997f;
#pragma unroll
  for (int n = 0; n < 4; n++) {
    int col = col0 + wc + n * 16 + fr;
    float s = 0.f, t = 0.f, bb = 0.f;
    if (EPI == 1) { s = inv * bng[col]; t = bias[col] * s + bnb[col]; }
    if (EPI == 2) { bb = (col < realN) ? bias[col] : 0.f; }
#pragma unroll
    for (int m = 0; m < 4; m++) {
      int rowb = row0 + wr + m * 16 + fq * 4;
#pragma unroll
      for (int r = 0; r < 4; r++) {
        int row = rowb + r;
        float v = acc[m][n][r];
        if (EPI == 0) {
          ((ushort_t*)outp)[(size_t)row * ldOut + col] = f2b(v);
        } else if (EPI == 1) {
          v = fmaxf(v * s + t, 0.f);
          ((ushort_t*)outp)[(size_t)row * ldOut + col] = f2b(v);
        } else if (EPI == 2) {
          if (row < realM && col < realN)
            ((float*)outp)[(size_t)row * ldOut + col] = v + bb;
        } else {
          if (row < realM && col < realN)
            ((float*)outp)[(size_t)row * ldOut + col] = v;
        }
      }
    }
  }
}

// ---------- gemm3: 128x256 tile, 4 waves, per-wave 128x64 (MR=8,NR=4), BK=32,
// 3 LDS bufs, depth-2 prefetch, ONE barrier + counted vmcnt per K-tile
// (vmcnt(6) steady-state; vmcnt(0) on final iter, tail dummy stages skipped).
// Row-major XCD-chunk traversal for A-panel L2 reuse.
// EPI 0: bf16 plain; 1: bf16 relu((v+b)*inv*g+be); 2: f32 v+bias guarded;
// 4: adj symmetric transposed float4 store (C == C^T), guarded.
template<int EPI>
__global__ __launch_bounds__(256, 2)
void gemm3(const ushort_t* __restrict__ A, const ushort_t* __restrict__ BT, int K,
           void* __restrict__ outp, int ldOut, int realM, int realN,
           const float* __restrict__ bias, const float* __restrict__ bng,
           const float* __restrict__ bnb)
{
  __shared__ ushort_t lA[3 * 128 * 32];
  __shared__ ushort_t lB[3 * 256 * 32];
  const int tid = threadIdx.x;
  const int wn  = tid >> 6;                 // 4 waves split N
  const int fr  = tid & 15, fq = (tid >> 4) & 3;

  int gy = gridDim.y;                        // # of 256-col tiles
  int nwg = gridDim.x * gy;
  int bid = blockIdx.y * gridDim.x + blockIdx.x;
  int q8 = nwg >> 3, r8 = nwg & 7;
  int xcd = bid & 7, j = bid >> 3;
  int swz = (xcd < r8 ? xcd * (q8 + 1) : r8 * (q8 + 1) + (xcd - r8) * q8) + j;
  const int row0 = (swz / gy) * 128;         // row-major: col fastest
  const int col0 = (swz % gy) * 256;

  f32x4 acc[8][4] = {};

  auto stA = [&](int p, int kt, int r) {
    int c = r * 256 + tid;
    int row = c >> 2, slot = c & 3;
    int ss = slot ^ ((row >> 1) & 3);              // pre-swizzled SOURCE
    gload16(A + (size_t)(row0 + row) * K + kt * 32 + ss * 8,
            &lA[p * (128 * 32) + c * 8]);          // linear LDS dest
  };
  auto stB = [&](int p, int kt, int r) {
    int c = r * 256 + tid;
    int row = c >> 2, slot = c & 3;
    int ss = slot ^ ((row >> 1) & 3);
    gload16(BT + (size_t)(col0 + row) * K + kt * 32 + ss * 8,
            &lB[p * (256 * 32) + c * 8]);
  };
  auto stage = [&](int p, int kt) {
    stA(p, kt, 0); stA(p, kt, 1);
    stB(p, kt, 0); stB(p, kt, 1); stB(p, kt, 2); stB(p, kt, 3);
  };

  const int NT = K >> 5;                    // requires NT >= 2 (all uses: >= 4)
  stage(0, 0);
  stage(1, 1);

  for (int t = 0; t < NT; ++t) {
    const int p = t % 3;
    const int s = (t + 2) % 3;              // buffer of tile t-1, reads done pre-barrier
    // Count ledger: iters t<NT-2 stage tile t+2 -> at iter top outstanding = 12
    // (tiles t, t+1), vmcnt(6) drains exactly tile t. Iters >= NT-2 skip staging,
    // so at t=NT-1 outstanding = 6 (tile NT-1 only) -> must drain all: vmcnt(0).
    if (t + 1 == NT) asm volatile("s_waitcnt vmcnt(0)" ::: "memory");
    else             asm volatile("s_waitcnt vmcnt(6)" ::: "memory");
    __builtin_amdgcn_s_barrier();
    asm volatile("" ::: "memory");
    if (t + 2 < NT) stage(s, t + 2);

    short8 bf[4], af[8];
#pragma unroll
    for (int n = 0; n < 4; ++n) {
      int rb = wn * 64 + n * 16 + fr;
      bf[n] = *(const short8*)&lB[p * (256 * 32) + rb * 32 + ((fq ^ ((rb >> 1) & 3)) * 8)];
    }
#pragma unroll
    for (int m = 0; m < 8; ++m) {
      int ra = m * 16 + fr;
      af[m] = *(const short8*)&lA[p * (128 * 32) + ra * 32 + ((fq ^ ((ra >> 1) & 3)) * 8)];
    }
    __builtin_amdgcn_s_setprio(1);
#pragma unroll
    for (int m = 0; m < 8; ++m)
#pragma unroll
      for (int n = 0; n < 4; ++n)
        acc[m][n] = __builtin_amdgcn_mfma_f32_16x16x32_bf16(af[m], bf[n], acc[m][n], 0, 0, 0);
    __builtin_amdgcn_s_setprio(0);
    asm volatile("" ::: "memory");
  }

  const float inv = 0.9999950000374997f;
#pragma unroll
  for (int n = 0; n < 4; ++n) {
    int col = col0 + wn * 64 + n * 16 + fr;
    float sc = 0.f, tc = 0.f, bb = 0.f;
    if (EPI == 1) { sc = inv * bng[col]; tc = bias[col] * sc + bnb[col]; }
    if (EPI == 2) { bb = (col < realN) ? bias[col] : 0.f; }
#pragma unroll
    for (int m = 0; m < 8; ++m) {
      int rowb = row0 + m * 16 + fq * 4;
      if (EPI == 4) {
        // C symmetric: store lane's 4 consecutive rows as 4 consecutive cols of row `col`
        if (col < realN && rowb < realM) {
          if (rowb + 4 <= realM) {
            float4 v4; v4.x = acc[m][n][0]; v4.y = acc[m][n][1];
            v4.z = acc[m][n][2]; v4.w = acc[m][n][3];
            *(float4*)((float*)outp + (size_t)col * ldOut + rowb) = v4;
          } else {
            for (int r = 0; r < realM - rowb; ++r)
              ((float*)outp)[(size_t)col * ldOut + rowb + r] = acc[m][n][r];
          }
        }
      } else {
#pragma unroll
        for (int r = 0; r < 4; ++r) {
          int row = rowb + r;
          float v = acc[m][n][r];
          if (EPI == 0) {
            ((ushort_t*)outp)[(size_t)row * ldOut + col] = f2b(v);
          } else if (EPI == 1) {
            v = fmaxf(v * sc + tc, 0.f);
            ((ushort_t*)outp)[(size_t)row * ldOut + col] = f2b(v);
          } else if (EPI == 2) {
            if (row < realM && col < realN)
              ((float*)outp)[(size_t)row * ldOut + col] = v + bb;
          }
        }
      }
    }
  }
}

// ---------- spmm1 L2-chunked + unroll-8 gather ----------
__global__ void spmm1c_k(const ushort_t* __restrict__ h, ushort_t* __restrict__ o,
                         const int* __restrict__ rs, const int* __restrict__ psrc,
                         const float* __restrict__ pw) {
  const int chunk = blockIdx.y;
  const int dst = blockIdx.x * 4 + (threadIdx.x >> 6);
  const int lane = threadIdx.x & 63;
  const int c0 = chunk * 128 + lane * 2;
  float a0 = 0.f, a1 = 0.f;
  if (dst < N_NODES) {
    const int s0 = rs[dst], e0 = rs[dst + 1];
    int i = s0;
    for (; i + 8 <= e0; i += 8) {
      int   sr[8]; float wv[8]; uint32_t v[8];
#pragma unroll
      for (int u = 0; u < 8; ++u) { sr[u] = psrc[i + u]; wv[u] = pw[i + u]; }
#pragma unroll
      for (int u = 0; u < 8; ++u) v[u] = *(const uint32_t*)&h[(size_t)sr[u] * H1 + c0];
#pragma unroll
      for (int u = 0; u < 8; ++u) {
        a0 += wv[u] * b2f((ushort_t)(v[u] & 0xffff));
        a1 += wv[u] * b2f((ushort_t)(v[u] >> 16));
      }
    }
    for (; i < e0; ++i) {
      float wv = pw[i];
      uint32_t v = *(const uint32_t*)&h[(size_t)psrc[i] * H1 + c0];
      a0 += wv * b2f((ushort_t)(v & 0xffff));
      a1 += wv * b2f((ushort_t)(v >> 16));
    }
  }
  uint32_t ov = (uint32_t)f2b(fmaxf(a0, 0.f)) | ((uint32_t)f2b(fmaxf(a1, 0.f)) << 16);
  *(uint32_t*)&o[(size_t)dst * H1 + c0] = ov;
}

// ---------- spmm2: wave-per-dst, 4 cols/lane, unroll-8 ----------
__global__ void spmm2_k(const ushort_t* __restrict__ pre, float* __restrict__ mu,
                        float* __restrict__ lv, float* __restrict__ zf,
                        ushort_t* __restrict__ zb,
                        const int* __restrict__ rs, const int* __restrict__ psrc,
                        const float* __restrict__ pw) {
  const int dst = blockIdx.x * 4 + (threadIdx.x >> 6);
  const int lane = threadIdx.x & 63;
  const int c0 = lane * 4;
  float a0 = 0.f, a1 = 0.f, a2 = 0.f, a3 = 0.f;
  if (dst < N_NODES) {
    const int s0 = rs[dst], e0 = rs[dst + 1];
    int i = s0;
    for (; i + 8 <= e0; i += 8) {
      int sr[8]; float wv[8]; uint2 v[8];
#pragma unroll
      for (int u = 0; u < 8; ++u) { sr[u] = psrc[i + u]; wv[u] = pw[i + u]; }
#pragma unroll
      for (int u = 0; u < 8; ++u) v[u] = *(const uint2*)&pre[(size_t)sr[u] * 256 + c0];
#pragma unroll
      for (int u = 0; u < 8; ++u) {
        a0 += wv[u] * b2f((ushort_t)(v[u].x & 0xffff));
        a1 += wv[u] * b2f((ushort_t)(v[u].x >> 16));
        a2 += wv[u] * b2f((ushort_t)(v[u].y & 0xffff));
        a3 += wv[u] * b2f((ushort_t)(v[u].y >> 16));
      }
    }
    for (; i < e0; ++i) {
      float wv = pw[i];
      uint2 v = *(const uint2*)&pre[(size_t)psrc[i] * 256 + c0];
      a0 += wv * b2f((ushort_t)(v.x & 0xffff));
      a1 += wv * b2f((ushort_t)(v.x >> 16));
      a2 += wv * b2f((ushort_t)(v.y & 0xffff));
      a3 += wv * b2f((ushort_t)(v.y >> 16));
    }
  }
  if (lane < 32) {
    uint2 zv;
    zv.x = (uint32_t)f2b(a0) | ((uint32_t)f2b(a1) << 16);
    zv.y = (uint32_t)f2b(a2) | ((uint32_t)f2b(a3) << 16);
    *(uint2*)&zb[(size_t)dst * 128 + c0] = zv;
    if (dst < N_NODES) {
      float4 m4; m4.x = a0; m4.y = a1; m4.z = a2; m4.w = a3;
      *(float4*)&mu[(size_t)dst * 128 + c0] = m4;
      *(float4*)&zf[(size_t)dst * 128 + c0] = m4;
    }
  } else if (dst < N_NODES) {
    float4 l4; l4.x = a0; l4.y = a1; l4.z = a2; l4.w = a3;
    *(float4*)&lv[(size_t)dst * 128 + (c0 - 128)] = l4;
  }
}

// ---------- host ----------
extern "C" void kernel_launch(void* const* d_in, const int* in_sizes, int n_in,
                              void* d_out, int out_size, void* d_ws, size_t ws_size,
                              hipStream_t stream) {
  (void)in_sizes; (void)n_in; (void)out_size; (void)ws_size;
  const float* x  = (const float*)d_in[0];
  const float* ew = (const float*)d_in[1];
  const float* W1 = (const float*)d_in[2];
  const float* W2 = (const float*)d_in[3];
  const float* W3 = (const float*)d_in[4];
  const float* fc_w[5] = {(const float*)d_in[5], (const float*)d_in[9],  (const float*)d_in[13], (const float*)d_in[17], (const float*)d_in[21]};
  const float* fc_b[5] = {(const float*)d_in[6], (const float*)d_in[10], (const float*)d_in[14], (const float*)d_in[18], (const float*)d_in[22]};
  const float* bn_g[4] = {(const float*)d_in[7], (const float*)d_in[11], (const float*)d_in[15], (const float*)d_in[19]};
  const float* bn_b[4] = {(const float*)d_in[8], (const float*)d_in[12], (const float*)d_in[16], (const float*)d_in[20]};
  const int* esrc = (const int*)d_in[23];
  const int* edst = (const int*)d_in[24];
  float* out = (float*)d_out;

  float* out_adj = out;
  float* out_mu  = out + (size_t)100000000;
  float* out_lv  = out + (size_t)101280000;
  float* out_z   = out + (size_t)102560000;
  float* out_xr  = out + (size_t)103840000;

  char* w = (char*)d_ws;
  size_t off = 0;
  auto alloc = [&](size_t bytes) { size_t o = off; off = (off + bytes + 255) & ~(size_t)255; return o; };
  int*      cnt  = (int*)(w + alloc(4 * N_NODES));
  int*      rs   = (int*)(w + alloc(4 * (N_NODES + 1)));
  int*      cur  = (int*)(w + alloc(4 * N_NODES));
  int*      psrc = (int*)(w + alloc(4 * E_EDGES));
  float*    pw   = (float*)(w + alloc(4 * E_EDGES));
  ushort_t* w1T  = (ushort_t*)(w + alloc((size_t)2 * 1024 * K1P));
  ushort_t* w23T = (ushort_t*)(w + alloc((size_t)2 * 256 * 1024));
  ushort_t* f1T  = (ushort_t*)(w + alloc((size_t)2 * 256 * 128));
  ushort_t* f2T  = (ushort_t*)(w + alloc((size_t)2 * 512 * 256));
  ushort_t* f3T  = (ushort_t*)(w + alloc((size_t)2 * 1024 * 512));
  ushort_t* f4T  = (ushort_t*)(w + alloc((size_t)2 * 2048 * 1024));
  ushort_t* f5T  = (ushort_t*)(w + alloc((size_t)2 * 3072 * 2048));
  ushort_t* xb   = (ushort_t*)(w + alloc((size_t)2 * MP * K1P));
  ushort_t* xw1b = (ushort_t*)(w + alloc((size_t)2 * MP * H1));
  ushort_t* h1b  = (ushort_t*)(w + alloc((size_t)2 * MP * H1));
  ushort_t* preb = (ushort_t*)(w + alloc((size_t)2 * MP * 256));
  ushort_t* zb   = (ushort_t*)(w + alloc((size_t)2 * MP * 128));
  ushort_t* act1 = xw1b;   // 10240 x 256
  ushort_t* act2 = xb;     // 10240 x 512
  ushort_t* act3 = h1b;    // 10240 x 1024
  ushort_t* act4 = xb;     // 10240 x 2048

  // ---- CSR build ----
  zero_k<<<(N_NODES + 255) / 256, 256, 0, stream>>>(cnt, N_NODES);
  count_k<<<(E_EDGES + 255) / 256, 256, 0, stream>>>(edst, cnt);
  scan_k<<<1, 256, 0, stream>>>(cnt, rs, cur);
  fill_k<<<(E_EDGES + 255) / 256, 256, 0, stream>>>(esrc, edst, ew, cur, psrc, pw);

  // ---- conversions ----
  conv_x_k<<<(MP * 376) / 256, 256, 0, stream>>>(x, xb);
  {
    SegPack P;
    int b0 = 0;
    auto mk = [&](const float* s, ushort_t* d, int K, int Nn, int Kp, int Np) {
      Seg sg; sg.src = s; sg.dst = d; sg.K = K; sg.Nn = Nn; sg.Kp = Kp; sg.Np = Np;
      sg.tilesN = Np / 32; sg.blk0 = b0;
      b0 += (Kp / 32) * (Np / 32);
      return sg;
    };
    P.s[0] = mk(W1,      w1T,                       D_IN, 1024, K1P,  1024);
    P.s[1] = mk(W2,      w23T,                      1024, 128,  1024, 128);
    P.s[2] = mk(W3,      w23T + (size_t)128 * 1024, 1024, 128,  1024, 128);
    P.s[3] = mk(fc_w[0], f1T,                       128,  256,  128,  256);
    P.s[4] = mk(fc_w[1], f2T,                       256,  512,  256,  512);
    P.s[5] = mk(fc_w[2], f3T,                       512,  1024, 512,  1024);
    P.s[6] = mk(fc_w[3], f4T,                       1024, 2048, 1024, 2048);
    P.s[7] = mk(fc_w[4], f5T,                       2048, 3000, 2048, 3072);
    conv_w_all_k<<<b0, 256, 0, stream>>>(P);
  }

  dim3 blk2(256);
  // ---- GEMM1: xb (MP x K1P) @ W1 -> xw1b bf16 (MP x 1024) ----
  gemm3<0><<<dim3(MP / 128, 1024 / 256), blk2, 0, stream>>>(xb, w1T, K1P, xw1b, 1024, MP, 1024, nullptr, nullptr, nullptr);
  // ---- spmm1 (L2-chunked, unroll-8) + relu -> h1b bf16 ----
  spmm1c_k<<<dim3(MP / 4, 8), blk2, 0, stream>>>(xw1b, h1b, rs, psrc, pw);
  // ---- GEMM2: h1b @ [W2|W3] -> preb bf16 (MP x 256) ----
  gemm_bt<0><<<dim3(MP / 128, 2), blk2, 0, stream>>>(h1b, w23T, 1024, preb, 256, MP, 256, nullptr, nullptr, nullptr);
  // ---- spmm2 (wave-per-dst, unroll-8) -> mu/logvar/z (f32) + zb bf16 ----
  spmm2_k<<<dim3(MP / 4), blk2, 0, stream>>>(preb, out_mu, out_lv, out_z, zb, rs, psrc, pw);
  // ---- adj = z @ z^T (f32, symmetric transposed float4 store) ----
  gemm3<4><<<dim3(MP / 128, MP / 256), blk2, 0, stream>>>(zb, zb, 128, out_adj, 10000, N_NODES, N_NODES, nullptr, nullptr, nullptr);
  // ---- FC stack ----
  gemm_bt<1><<<dim3(MP / 128, 2), blk2, 0, stream>>>(zb,   f1T, 128,  act1, 256,  MP, 256,  fc_b[0], bn_g[0], bn_b[0]);
  gemm_bt<1><<<dim3(MP / 128, 4), blk2, 0, stream>>>(act1, f2T, 256,  act2, 512,  MP, 512,  fc_b[1], bn_g[1], bn_b[1]);
  gemm3<1><<<dim3(MP / 128, 1024 / 256), blk2, 0, stream>>>(act2, f3T, 512,  act3, 1024, MP, 1024, fc_b[2], bn_g[2], bn_b[2]);
  gemm3<1><<<dim3(MP / 128, 2048 / 256), blk2, 0, stream>>>(act3, f4T, 1024, act4, 2048, MP, 2048, fc_b[3], bn_g[3], bn_b[3]);
  gemm3<2><<<dim3(MP / 128, 3072 / 256), blk2, 0, stream>>>(act4, f5T, 2048, out_xr, 3000, N_NODES, 3000, fc_b[4], nullptr, nullptr);
}